// Round 1
// 8609.651 us; speedup vs baseline: 1.9731x; 1.9731x over previous
//
#include <hip/hip_runtime.h>

// Problem constants
#define NB   128
#define LSEQ 2048
#define HID  512
#define EMB  256
#define KD   768
// Structure: batch rows are INDEPENDENT. 8 n-groups x 16 n; each group split
// over 32 h-blocks x 16 h. 256 blocks, 512 threads = 8 waves, K split 96/wave.
#define NGRP  8
#define NPG   16
#define HBLK  32
#define HPB   16
#define NWG   256
#define NTHR  512
#define RING  4
#define KSL   96
#define FPAD  64   // ints per flag slot (256 B): one producer per cache line

#define AT_RLX __ATOMIC_RELAXED
#define AT_REL __ATOMIC_RELEASE
#define SCOPE  __HIP_MEMORY_SCOPE_AGENT

typedef unsigned long long ull;
typedef _Float16 f16;
typedef f16   f16x8 __attribute__((ext_vector_type(8)));
typedef float f32x4 __attribute__((ext_vector_type(4)));

__device__ __forceinline__ float sigf(float x) { return 1.0f / (1.0f + __expf(-x)); }
__device__ __forceinline__ float tanhfast(float x) { return fmaf(-2.0f, 1.0f / (1.0f + __expf(2.0f * x)), 1.0f); }

// Drain this wave's vmem (stores ack'd at LLC) then lane0 publishes the flag.
__device__ __forceinline__ void publish_flag(int* fl, int val, int is_l0) {
#if __has_builtin(__builtin_amdgcn_s_waitcnt)
    __builtin_amdgcn_s_waitcnt(0);
    if (is_l0) __hip_atomic_store(fl, val, AT_RLX, SCOPE);
#else
    if (is_l0) __hip_atomic_store(fl, val, AT_REL, SCOPE);
#endif
}

__global__ void __launch_bounds__(NTHR, 2)
lstm_pers(const int* __restrict__ X, const float* __restrict__ E,
          const float* __restrict__ Ww, const float* __restrict__ Wb,
          float* __restrict__ out, float* __restrict__ ws)
{
    const int tid  = threadIdx.x;
    const int bid  = blockIdx.x;
    const int ng   = bid & (NGRP - 1);     // n-group (bid&7 -> XCD-local heuristic)
    const int hb   = bid >> 3;             // h-block 0..31
    const int w    = tid >> 6;             // wave 0..7
    const int lane = tid & 63;
    const int quad = lane >> 4;
    const int m16  = lane & 15;
    const int ks   = w * KSL;              // this wave's K base (96 wide)

    // Padded reduction buffer: row stride 20 floats (80 B). For the f32x4
    // deposit at [m16][quad*4] the bank start = (20*m16 + 4*quad) % 32 is
    // uniform (8 lanes per 4-bank group) -> conflict-free deposit AND reduce.
    // Single buffer is safe: next-step deposits happen only after the poll
    // barrier, which wave 7 reaches only after its reduce-reads are done.
    __shared__ float red[8][4][16][20];    // 40 KB

    // Hbuf layout: [ng][slot][hb][n=16][h=16] fp16 -> each producer owns a
    // contiguous 512 B block (4 cache lines, SINGLE writer; no false sharing).
    f16* Hbuf  = (f16*)ws;
    // flags: [ng][hb], padded to 256 B each -> one writer + its pollers per line.
    int* flags = (int*)((char*)ws + (size_t)NGRP * RING * HBLK * NPG * HPB * 2);

    // ---- init: W fragments -> VGPRs (fp16), persistent for whole kernel ----
    // A-frag layout (16x16x32): lane holds A[m=lane&15][k=quad*8+j], j=0..7.
    // M-tile = gate g (16 rows = the 16 h of this block), K-tiles ti=0..2.
    f16x8 wf[4][3];
    #pragma unroll
    for (int g = 0; g < 4; ++g) {
        #pragma unroll
        for (int ti = 0; ti < 3; ++ti) {
            const float* wp = Ww + (size_t)(g * HID + hb * HPB + m16) * KD
                                 + (ks + ti * 32 + quad * 8);
            f16x8 v;
            #pragma unroll
            for (int j = 0; j < 8; ++j) v[j] = (f16)wp[j];
            wf[g][ti] = v;
        }
    }
    // bias + cell state live in wave 7 (the epilogue wave)
    f32x4 bias[4], cst = {0, 0, 0, 0};
    if (w == 7) {
        #pragma unroll
        for (int g = 0; g < 4; ++g)
            bias[g] = *(const f32x4*)(Wb + g * HID + hb * HPB + quad * 4);
        // zero own H(0) block in slot 0: 64 lanes x 8 B = 512 B
        ull* z = (ull*)(Hbuf + ((size_t)(ng * RING + 0) * HBLK + hb) * (NPG * HPB)
                        + lane * 4);
        __hip_atomic_store(z, 0ull, AT_RLX, SCOPE);
    }
    __syncthreads();
    if (w == 7) publish_flag(&flags[(ng * HBLK + hb) * FPAD], 0, lane == 0);

    // wave 6 is the poll wave: 32 lanes cover all 32 producers of this group
    // (lanes 32-63 duplicate lanes 0-31 -> same lines, harmless).
    const int* fp6 = flags + (size_t)(ng * HBLK + (lane & (HBLK - 1))) * FPAD;

    for (int t = 0; t < LSEQ; ++t) {
        f16x8 bf[3];
        // ---- E tiles first (cached reads, in flight during the poll) ----
        if (ks + 2 * 32 >= HID) {                    // wave has >=1 E tile
            int xi = X[(ng * NPG + m16) * LSEQ + t];
            const float* eb = E + (size_t)xi * EMB;
            #pragma unroll
            for (int ti = 0; ti < 3; ++ti) {
                int k0 = ks + ti * 32;
                if (k0 >= HID) {
                    const float* ep = eb + (k0 - HID) + quad * 8;
                    f32x4 e0 = *(const f32x4*)(ep);
                    f32x4 e1 = *(const f32x4*)(ep + 4);
                    f16x8 v;
                    #pragma unroll
                    for (int j = 0; j < 4; ++j) { v[j] = (f16)e0[j]; v[4 + j] = (f16)e1[j]; }
                    bf[ti] = v;
                }
            }
        }
        // ---- single poll wave: wave 6 waits for all 32 producer flags ----
        if (w == 6) {
            while (!__all(__hip_atomic_load(fp6, AT_RLX, SCOPE) >= t))
                __builtin_amdgcn_s_sleep(1);
        }
        __syncthreads();                   // bar_poll: H(t) fully published
        // ---- H tiles from producer-contiguous blocks: 16 B/lane coalesced ----
        const f16* Hc = Hbuf + (size_t)(ng * RING + (t & 3)) * HBLK * (NPG * HPB);
        #pragma unroll
        for (int ti = 0; ti < 3; ++ti) {
            int k0 = ks + ti * 32;
            if (k0 < HID) {
                int k = k0 + quad * 8;     // 8-aligned, stays inside one 16-h block
                const ull* hp = (const ull*)(Hc + (size_t)(k >> 4) * (NPG * HPB)
                                             + m16 * HPB + (k & 15));
                union { ull u[2]; f16x8 v; } cv;
                cv.u[0] = __hip_atomic_load(hp,     AT_RLX, SCOPE);
                cv.u[1] = __hip_atomic_load(hp + 1, AT_RLX, SCOPE);
                bf[ti] = cv.v;
            }
        }
        // ---- MFMA: 4 gates x 3 K-tiles ----
        f32x4 acc[4] = {{0,0,0,0},{0,0,0,0},{0,0,0,0},{0,0,0,0}};
        #pragma unroll
        for (int ti = 0; ti < 3; ++ti)
            #pragma unroll
            for (int g = 0; g < 4; ++g)
                acc[g] = __builtin_amdgcn_mfma_f32_16x16x32_f16(wf[g][ti], bf[ti], acc[g], 0, 0, 0);

        // ---- deposit partials (conflict-free padded layout) ----
        #pragma unroll
        for (int g = 0; g < 4; ++g)
            *(f32x4*)&red[w][g][m16][quad * 4] = acc[g];
        __syncthreads();                   // bar_dep: all partials visible

        if (w == 7) {
            // reduce 8 waves, add bias: lane owns n=m16, h = quad*4 .. +3
            f32x4 G[4];
            #pragma unroll
            for (int g = 0; g < 4; ++g) {
                f32x4 s = bias[g];
                #pragma unroll
                for (int wv = 0; wv < 8; ++wv) {
                    f32x4 r = *(const f32x4*)&red[wv][g][m16][quad * 4];
                    s.x += r.x; s.y += r.y; s.z += r.z; s.w += r.w;
                }
                G[g] = s;
            }
            // gates + cell update; 4 h's per lane, contiguous -> one 8B store
            union { f16 h[4]; ull u; } pk;
            f32x4 ov;
            #pragma unroll
            for (int s = 0; s < 4; ++s) {
                float F = sigf(G[0][s]);
                float I = sigf(G[1][s]);
                float O = sigf(G[2][s]);
                float T = tanhfast(G[3][s]);
                cst[s] = fmaf(F, cst[s], I * T);
                float hn = O * tanhfast(cst[s]);
                pk.h[s] = (f16)hn;
                ov[s] = hn;
            }
            // own 512 B block, single writer: base + m16*16 + quad*4 (f16 units)
            f16* Hw = Hbuf + ((size_t)(ng * RING + ((t + 1) & 3)) * HBLK + hb)
                             * (NPG * HPB);
            __hip_atomic_store((ull*)(Hw + m16 * HPB + quad * 4),
                               pk.u, AT_RLX, SCOPE);
            if (t == LSEQ - 1)
                *(f32x4*)(out + (size_t)(ng * NPG + m16) * HID + hb * HPB + quad * 4) = ov;
            publish_flag(&flags[(ng * HBLK + hb) * FPAD], t + 1, lane == 0);
        }
        // Slot safety (RING=4): a producer reaches epilogue(t) only after all
        // flags >= t, i.e. every block finished step t-1 and thus its reads of
        // slot (t+1)&3 (done at step t-3). Writes at t and reads at t-3 of the
        // same slot can never overlap.
    }
}

extern "C" void kernel_launch(void* const* d_in, const int* in_sizes, int n_in,
                              void* d_out, int out_size, void* d_ws, size_t ws_size,
                              hipStream_t stream) {
    const int*   X   = (const int*)d_in[0];
    const float* E   = (const float*)d_in[1];
    const float* Ww  = (const float*)d_in[2];
    const float* Wb  = (const float*)d_in[3];
    float*       out = (float*)d_out;
    float*       ws  = (float*)d_ws;
    void* args[] = { (void*)&X, (void*)&E, (void*)&Ww, (void*)&Wb, (void*)&out, (void*)&ws };
    hipError_t e = hipLaunchCooperativeKernel((const void*)lstm_pers, dim3(NWG), dim3(NTHR),
                                              args, 0, stream);
    if (e != hipSuccess) {
        // 256 blocks, 40KB LDS, low VGPR -> 1 block/CU co-resident on 256 CUs.
        hipLaunchKernelGGL(lstm_pers, dim3(NWG), dim3(NTHR), 0, stream,
                           X, E, Ww, Wb, out, ws);
    }
}

// Round 5
// 6952.303 us; speedup vs baseline: 2.4435x; 1.2384x over previous
//
#include <hip/hip_runtime.h>

// Problem constants
#define NB   128
#define LSEQ 2048
#define HID  512
#define EMB  256
#define KD   768
// Structure: batch rows are INDEPENDENT. 8 n-groups x 16 n; each group split
// over 32 h-blocks x 16 h. 256 blocks, 512 threads = 8 waves, K split 96/wave.
#define NGRP  8
#define NPG   16
#define HBLK  32
#define HPB   16
#define NWG   256
#define NTHR  512
#define RING  4
#define KSL   96
#define FPAD  64   // ints per flag slot (256 B): one producer per cache line
// Sentinel: 4x f16 0xFFFF (NaN). h = O*tanh(C) is always finite, and f16
// conversion of a finite float can never produce 0xFFFF, so valid data never
// aliases the sentinel. Each 8B word is written by ONE store -> no tearing.
#define SENT 0xFFFFFFFFFFFFFFFFull

#define AT_RLX __ATOMIC_RELAXED
#define SCOPE  __HIP_MEMORY_SCOPE_AGENT

typedef unsigned long long ull;
typedef _Float16 f16;
typedef f16   f16x8 __attribute__((ext_vector_type(8)));
typedef float f32x4 __attribute__((ext_vector_type(4)));

__device__ __forceinline__ float sigf(float x) { return 1.0f / (1.0f + __expf(-x)); }
__device__ __forceinline__ float tanhfast(float x) { return fmaf(-2.0f, 1.0f / (1.0f + __expf(2.0f * x)), 1.0f); }

// Drain this wave's vmem (stores ack'd at LLC) then lane0 publishes the flag.
__device__ __forceinline__ void publish_flag(int* fl, int val, int is_l0) {
    __builtin_amdgcn_s_waitcnt(0);
    if (is_l0) __hip_atomic_store(fl, val, AT_RLX, SCOPE);
}

__global__ void __launch_bounds__(NTHR, 2)
lstm_pers(const int* __restrict__ X, const float* __restrict__ E,
          const float* __restrict__ Ww, const float* __restrict__ Wb,
          float* __restrict__ out, float* __restrict__ ws)
{
    const int tid  = threadIdx.x;
    const int bid  = blockIdx.x;
    const int ng   = bid & (NGRP - 1);     // n-group (bid&7 -> XCD-local heuristic)
    const int hb   = bid >> 3;             // h-block 0..31
    const int w    = tid >> 6;             // wave 0..7
    const int lane = tid & 63;
    const int quad = lane >> 4;
    const int m16  = lane & 15;
    const int ks   = w * KSL;              // this wave's K base (96 wide)
    const int koff = quad * 8;

    // Padded reduction buffer: row stride 20 floats (80 B) -> conflict-free
    // f32x4 deposit AND reduce. Single buffer is safe: next-step deposits only
    // happen after bar A(t+1), which wave 7 reaches after its reduce reads.
    __shared__ float red[8][4][16][20];    // 40 KB

    // Hbuf layout: [ng][slot][hb][n=16][h=16] fp16 -> each producer owns a
    // contiguous 512 B block (single writer; no false sharing).
    f16* Hbuf  = (f16*)ws;
    // flags: [ng][hb], padded to 256 B each. Used ONLY for the t==1 rendezvous.
    int* flags = (int*)((char*)ws + (size_t)NGRP * RING * HBLK * NPG * HPB * 2);

    // ---- init: W fragments -> VGPRs (fp16), persistent for whole kernel ----
    // A-frag layout (16x16x32): lane holds A[m=lane&15][k=quad*8+j], j=0..7.
    f16x8 wf[4][3];
    #pragma unroll
    for (int g = 0; g < 4; ++g) {
        #pragma unroll
        for (int ti = 0; ti < 3; ++ti) {
            const float* wp = Ww + (size_t)(g * HID + hb * HPB + m16) * KD
                                 + (ks + ti * 32 + koff);
            f16x8 v;
            #pragma unroll
            for (int j = 0; j < 8; ++j) v[j] = (f16)wp[j];
            wf[g][ti] = v;
        }
    }
    // bias + cell state live in wave 7 (the epilogue wave)
    f32x4 bias[4], cst = {0, 0, 0, 0};
    if (w == 7) {
        #pragma unroll
        for (int g = 0; g < 4; ++g)
            bias[g] = *(const f32x4*)(Wb + g * HID + hb * HPB + quad * 4);
        // Sentinel-fill own 512B block in slots 2 and 3 (read first at t=2,3).
        // Slot 1 needs no sentinel: the t==1 flag rendezvous guarantees its
        // data landed. Slot 0 is first read at t=4 (filled at epilogue 1).
        // These fills are drained by epilogue-0's publish_flag before any
        // consumer can pass the t==1 rendezvous.
        #pragma unroll
        for (int s = 2; s <= 3; ++s) {
            ull* z = (ull*)(Hbuf + ((size_t)(ng * RING + s) * HBLK + hb)
                            * (NPG * HPB) + lane * 4);
            __hip_atomic_store(z, SENT, AT_RLX, SCOPE);
        }
    }
    __syncthreads();

    // wave 6 polls the 32 producer flags once, at t==1.
    const int* fp6 = flags + (size_t)(ng * HBLK + (lane & (HBLK - 1))) * FPAD;
    int* myflag = &flags[(ng * HBLK + hb) * FPAD];
    const int nh = (ks + 64 < HID) ? 3 : ((ks < HID) ? 1 : 0);

    for (int t = 0; t < LSEQ; ++t) {
        f16x8 bf[3];
        // ---- E tiles first (plain cached reads, in flight during poll) ----
        if (ks + 64 >= HID) {                    // wave has >=1 E tile
            int xi = X[(ng * NPG + m16) * LSEQ + t];
            const float* eb = E + (size_t)xi * EMB;
            #pragma unroll
            for (int ti = 0; ti < 3; ++ti) {
                int k0 = ks + ti * 32;
                if (k0 >= HID) {
                    const float* ep = eb + (k0 - HID) + koff;
                    f32x4 e0 = *(const f32x4*)(ep);
                    f32x4 e1 = *(const f32x4*)(ep + 4);
                    f16x8 v;
                    #pragma unroll
                    for (int j = 0; j < 4; ++j) { v[j] = (f16)e0[j]; v[4 + j] = (f16)e1[j]; }
                    bf[ti] = v;
                }
            }
        }
        // ---- one-time rendezvous: all producers published H(1) + init fills ----
        if (w == 6 && t == 1) {
            while (!__all(__hip_atomic_load(fp6, AT_RLX, SCOPE) >= 1))
                __builtin_amdgcn_s_sleep(1);
        }
        __syncthreads();               // bar A: red reusable; t==1 H published
        // ---- H tiles: sentinel-validated self-service (no flags, no drain) ----
        if (t == 0) {
            f16x8 z;
            #pragma unroll
            for (int j = 0; j < 8; ++j) z[j] = (f16)0.0f;
            for (int ti = 0; ti < nh; ++ti) bf[ti] = z;
        } else if (nh == 3) {
            const f16* Hc = Hbuf + (size_t)(ng * RING + (t & 3)) * HBLK * (NPG * HPB);
            int ka = ks + koff, kb = ka + 32, kc = kb + 32;
            const ull* h0 = (const ull*)(Hc + (size_t)(ka >> 4) * (NPG * HPB) + m16 * HPB + (ka & 15));
            const ull* h1 = (const ull*)(Hc + (size_t)(kb >> 4) * (NPG * HPB) + m16 * HPB + (kb & 15));
            const ull* h2 = (const ull*)(Hc + (size_t)(kc >> 4) * (NPG * HPB) + m16 * HPB + (kc & 15));
            ull u0, u1, u2, u3, u4, u5;
            for (;;) {
                u0 = __hip_atomic_load(h0,     AT_RLX, SCOPE);
                u1 = __hip_atomic_load(h0 + 1, AT_RLX, SCOPE);
                u2 = __hip_atomic_load(h1,     AT_RLX, SCOPE);
                u3 = __hip_atomic_load(h1 + 1, AT_RLX, SCOPE);
                u4 = __hip_atomic_load(h2,     AT_RLX, SCOPE);
                u5 = __hip_atomic_load(h2 + 1, AT_RLX, SCOPE);
                bool ok = (u0 != SENT) & (u1 != SENT) & (u2 != SENT)
                        & (u3 != SENT) & (u4 != SENT) & (u5 != SENT);
                if (__all(ok)) break;
                __builtin_amdgcn_s_sleep(1);
            }
            union { ull u[2]; f16x8 v; } c;
            c.u[0] = u0; c.u[1] = u1; bf[0] = c.v;
            c.u[0] = u2; c.u[1] = u3; bf[1] = c.v;
            c.u[0] = u4; c.u[1] = u5; bf[2] = c.v;
        } else if (nh == 1) {
            const f16* Hc = Hbuf + (size_t)(ng * RING + (t & 3)) * HBLK * (NPG * HPB);
            int ka = ks + koff;
            const ull* h0 = (const ull*)(Hc + (size_t)(ka >> 4) * (NPG * HPB) + m16 * HPB + (ka & 15));
            ull u0, u1;
            for (;;) {
                u0 = __hip_atomic_load(h0,     AT_RLX, SCOPE);
                u1 = __hip_atomic_load(h0 + 1, AT_RLX, SCOPE);
                if (__all((u0 != SENT) & (u1 != SENT))) break;
                __builtin_amdgcn_s_sleep(1);
            }
            union { ull u[2]; f16x8 v; } c;
            c.u[0] = u0; c.u[1] = u1; bf[0] = c.v;
        }
        // ---- MFMA: 4 gates x 3 K-tiles ----
        f32x4 acc[4] = {{0,0,0,0},{0,0,0,0},{0,0,0,0},{0,0,0,0}};
        #pragma unroll
        for (int ti = 0; ti < 3; ++ti)
            #pragma unroll
            for (int g = 0; g < 4; ++g)
                acc[g] = __builtin_amdgcn_mfma_f32_16x16x32_f16(wf[g][ti], bf[ti], acc[g], 0, 0, 0);

        // ---- deposit partials (conflict-free padded layout) ----
        #pragma unroll
        for (int g = 0; g < 4; ++g)
            *(f32x4*)&red[w][g][m16][quad * 4] = acc[g];
        __syncthreads();               // bar B: all partials visible

        if (w == 7) {
            f32x4 G[4];
            #pragma unroll
            for (int g = 0; g < 4; ++g) {
                f32x4 s = bias[g];
                #pragma unroll
                for (int wv = 0; wv < 8; ++wv) {
                    f32x4 r = *(const f32x4*)&red[wv][g][m16][quad * 4];
                    s.x += r.x; s.y += r.y; s.z += r.z; s.w += r.w;
                }
                G[g] = s;
            }
            union { f16 h[4]; ull u; } pk;
            f32x4 ov;
            #pragma unroll
            for (int s = 0; s < 4; ++s) {
                float F = sigf(G[0][s]);
                float I = sigf(G[1][s]);
                float O = sigf(G[2][s]);
                float T = tanhfast(G[3][s]);
                cst[s] = fmaf(F, cst[s], I * T);
                float hn = O * tanhfast(cst[s]);
                pk.h[s] = (f16)hn;
                ov[s] = hn;
            }
            if (t < LSEQ - 1) {
                // Drain: guarantees the sentinel for slot (t+1)&3 (issued at
                // epilogue t-2, so ~1 full step old -> this wait is free) has
                // landed before data overwrites it.
                __builtin_amdgcn_s_waitcnt(0);
                f16* Hw = Hbuf + ((size_t)(ng * RING + ((t + 1) & 3)) * HBLK + hb)
                                 * (NPG * HPB);
                __hip_atomic_store((ull*)(Hw + m16 * HPB + quad * 4), pk.u,
                                   AT_RLX, SCOPE);
                if (t == 0) {
                    // one-time: drain data + init sentinels, then flag=1
                    publish_flag(myflag, 1, lane == 0);
                } else if (t + 3 < LSEQ) {
                    // Sentinel-fill slot (t+3)&3 for its next incarnation.
                    // Readers of its PREVIOUS data (step t-1) are provably done:
                    // we saw full H(t) => every block passed bar B(t-1).
                    // It lands before any consumer polls it at step t+3: it is
                    // drained by epilogue (t+1)'s waitcnt, which precedes the
                    // data consumers must see to even reach step t+2.
                    f16* Hs = Hbuf + ((size_t)(ng * RING + ((t + 3) & 3)) * HBLK + hb)
                                     * (NPG * HPB);
                    __hip_atomic_store((ull*)(Hs + m16 * HPB + quad * 4), SENT,
                                       AT_RLX, SCOPE);
                }
            } else {
                *(f32x4*)(out + (size_t)(ng * NPG + m16) * HID + hb * HPB + quad * 4) = ov;
            }
        }
        // Slot safety (RING=4): producer reaches epilogue t only after seeing
        // all of H(t), i.e. every block passed bar B(t-1), i.e. all reads of
        // H(t-1) and earlier are complete.
    }
}

extern "C" void kernel_launch(void* const* d_in, const int* in_sizes, int n_in,
                              void* d_out, int out_size, void* d_ws, size_t ws_size,
                              hipStream_t stream) {
    const int*   X   = (const int*)d_in[0];
    const float* E   = (const float*)d_in[1];
    const float* Ww  = (const float*)d_in[2];
    const float* Wb  = (const float*)d_in[3];
    float*       out = (float*)d_out;
    float*       ws  = (float*)d_ws;
    void* args[] = { (void*)&X, (void*)&E, (void*)&Ww, (void*)&Wb,
                     (void*)&out, (void*)&ws };
    hipError_t e = hipLaunchCooperativeKernel((const void*)lstm_pers, dim3(NWG), dim3(NTHR),
                                              args, 0, stream);
    if (e != hipSuccess) {
        // 256 blocks, 40KB LDS, ~64 VGPR -> 1 block/CU co-resident on 256 CUs.
        hipLaunchKernelGGL(lstm_pers, dim3(NWG), dim3(NTHR), 0, stream,
                           X, E, Ww, Wb, out, ws);
    }
}